// Round 1
// baseline (54.879 us; speedup 1.0000x reference)
//
#include <hip/hip_runtime.h>

// PhysConstrainedLES: fused divergence + pressure-Poisson RHS stencils.
// uPred: [B,2,H,W] f32, pPred: [B,1,H,W] f32
// out:  div [B,1,510,512] then pstar [B,1,510,510], concatenated flat, f32.

#define BN 32
#define HH 512
#define WW 512
#define OH 510   // output rows (H-2)
#define OW2 510  // pstar cols (W-2)

__global__ __launch_bounds__(256) void pcles_kernel(
    const float* __restrict__ u_,   // [B,2,H,W]
    const float* __restrict__ p_,   // [B,1,H,W]
    float* __restrict__ div_out,    // [B,510,512]
    float* __restrict__ ps_out)     // [B,510,510]
{
    const int w = blockIdx.x * 256 + threadIdx.x;   // 0..511
    const int h = blockIdx.y;                        // 0..509
    const int b = blockIdx.z;

    const float* ub = u_ + (size_t)b * 2 * HH * WW;
    const float* vb = ub + HH * WW;
    const float* pb = p_ + (size_t)b * HH * WW;

    const float dx = 0.01f, dy = 0.01f;
    const float inv2dx = 1.0f / (2.0f * dx);   // 50
    const float inv2dy = 1.0f / (2.0f * dy);   // 50
    const float invdx2 = 1.0f / (dx * dx);     // 1e4
    const float invdy2 = 1.0f / (dy * dy);     // 1e4

    // ---- divergence (width edge-padded via clamp) ----
    const int wm1 = (w > 0) ? (w - 1) : 0;
    const int wp1 = (w < WW - 1) ? (w + 1) : (WW - 1);
    const float dudx = (ub[(h + 1) * WW + wp1] - ub[(h + 1) * WW + wm1]) * inv2dx;
    const float dvdy = (vb[(h + 2) * WW + w] - vb[h * WW + w]) * inv2dy;
    float dv = dx * (dvdy + dudx);
    dv = fminf(fmaxf(dv, -1.0f), 1.0f);
    div_out[((size_t)b * OH + h) * WW + w] = dv;

    // ---- pressure-Poisson rhs (VALID grid, center (h+1, w+1)) ----
    if (w < OW2) {
        const float c = pb[(h + 1) * WW + w + 1];
        const float ddp =
            (pb[(h + 1) * WW + w] - 2.0f * c + pb[(h + 1) * WW + w + 2]) * invdx2 +
            (pb[h * WW + w + 1]   - 2.0f * c + pb[(h + 2) * WW + w + 1]) * invdy2;
        const float ux = (ub[(h + 1) * WW + w + 2] - ub[(h + 1) * WW + w]) * inv2dx;
        const float uy = (ub[(h + 2) * WW + w + 1] - ub[h * WW + w + 1]) * inv2dy;
        const float vx = (vb[(h + 1) * WW + w + 2] - vb[(h + 1) * WW + w]) * inv2dx;
        const float vy = (vb[(h + 2) * WW + w + 1] - vb[h * WW + w + 1]) * inv2dy;
        const float rhs = ux * ux + 2.0f * uy * vx + vy * vy;
        float ps = dx * dy * (ddp + rhs);
        ps = fminf(fmaxf(ps, -1.0f), 1.0f);
        ps_out[((size_t)b * OH + h) * OW2 + w] = ps;
    }
}

extern "C" void kernel_launch(void* const* d_in, const int* in_sizes, int n_in,
                              void* d_out, int out_size, void* d_ws, size_t ws_size,
                              hipStream_t stream) {
    const float* uPred = (const float*)d_in[0];
    const float* pPred = (const float*)d_in[1];
    float* div_out = (float*)d_out;
    float* ps_out  = div_out + (size_t)BN * OH * WW;  // 8,355,840 floats

    dim3 grid(WW / 256, OH, BN);   // (2, 510, 32)
    dim3 block(256, 1, 1);
    pcles_kernel<<<grid, block, 0, stream>>>(uPred, pPred, div_out, ps_out);
}

// Round 2
// 38.774 us; speedup vs baseline: 1.4154x; 1.4154x over previous
//
#include <hip/hip_runtime.h>

// PhysConstrainedLES: fused divergence + pressure-Poisson RHS stencils.
// uPred: [B,2,H,W] f32, pPred: [B,1,H,W] f32
// out:  div [B,510,512] then pstar [B,510,510], concatenated flat, f32.
//
// Each thread: 4 columns (float4) x 6-row strip, 3-row register window
// rotation (guaranteed vertical reuse). XCD-swizzled 1D grid so adjacent
// strips share an XCD L2 (halo rows hit L2, not HBM).

#define BN 32
#define HH 512
#define WW 512
#define OH 510
#define OW2 510
#define RSTRIP 6
#define NSTRIP 85            // 510 / 6
#define NBLK (NSTRIP * BN)   // 2720, divisible by 8

__device__ __forceinline__ float clip1(float x) {
    return fminf(fmaxf(x, -1.0f), 1.0f);
}

__global__ __launch_bounds__(128) void pcles_kernel(
    const float* __restrict__ u_,   // [B,2,H,W]
    const float* __restrict__ p_,   // [B,1,H,W]
    float* __restrict__ div_out,    // [B,510,512]
    float* __restrict__ ps_out)     // [B,510,510]
{
    // bijective XCD swizzle: each of the 8 XCDs gets a contiguous run of
    // 340 (strip,b) indices -> vertically adjacent strips share an L2.
    const int bid = blockIdx.x;
    const int nb  = (bid & 7) * (NBLK / 8) + (bid >> 3);
    const int strip = nb % NSTRIP;
    const int b     = nb / NSTRIP;
    const int h0 = strip * RSTRIP;
    const int wc = (int)threadIdx.x * 4;   // 0, 4, ..., 508

    const float* ub = u_ + (size_t)b * 2 * HH * WW;
    const float* vb = ub + HH * WW;
    const float* pb = p_ + (size_t)b * HH * WW;

    // clamped halo columns (replicate-pad semantics fall out automatically)
    const int cL = (wc > 0) ? wc - 1 : 0;
    const int c4 = (wc + 4 < WW) ? wc + 4 : WW - 1;
    const int c5 = (wc + 5 < WW) ? wc + 5 : WW - 1;

    // register windows: u cols wc-1..wc+5, v/p cols wc..wc+5, 3 rows rotating
    float uw[3][7], vw[3][6], pw[3][6];

    auto load_row = [&](int hh, int s) {
        const float* ur = ub + hh * WW;
        const float* vr = vb + hh * WW;
        const float* pr = pb + hh * WW;
        float4 t;
        t = *(const float4*)(ur + wc);
        uw[s][1] = t.x; uw[s][2] = t.y; uw[s][3] = t.z; uw[s][4] = t.w;
        uw[s][0] = ur[cL]; uw[s][5] = ur[c4]; uw[s][6] = ur[c5];
        t = *(const float4*)(vr + wc);
        vw[s][0] = t.x; vw[s][1] = t.y; vw[s][2] = t.z; vw[s][3] = t.w;
        vw[s][4] = vr[c4]; vw[s][5] = vr[c5];
        t = *(const float4*)(pr + wc);
        pw[s][0] = t.x; pw[s][1] = t.y; pw[s][2] = t.z; pw[s][3] = t.w;
        pw[s][4] = pr[c4]; pw[s][5] = pr[c5];
    };

    load_row(h0, 0);
    load_row(h0 + 1, 1);

    #pragma unroll
    for (int it = 0; it < RSTRIP; ++it) {
        const int s0 = it % 3, s1 = (it + 1) % 3, s2 = (it + 2) % 3;
        load_row(h0 + 2 + it, s2);
        const int h = h0 + it;

        float dv[4], ps[4];
        #pragma unroll
        for (int j = 0; j < 4; ++j) {
            // output col c = wc + j; u window idx of col c is (c - wc) + 1
            const float dudx = (uw[s1][j + 2] - uw[s1][j]) * 50.0f;
            const float dvdy = (vw[s2][j] - vw[s0][j]) * 50.0f;
            dv[j] = clip1(0.01f * (dvdy + dudx));

            const float pc  = pw[s1][j + 1];
            const float ddp = (pw[s1][j] - 2.0f * pc + pw[s1][j + 2]) * 1.0e4f
                            + (pw[s0][j + 1] - 2.0f * pc + pw[s2][j + 1]) * 1.0e4f;
            const float ux = (uw[s1][j + 3] - uw[s1][j + 1]) * 50.0f;
            const float uy = (uw[s2][j + 2] - uw[s0][j + 2]) * 50.0f;
            const float vx = (vw[s1][j + 2] - vw[s1][j]) * 50.0f;
            const float vy = (vw[s2][j + 1] - vw[s0][j + 1]) * 50.0f;
            const float rhs = ux * ux + 2.0f * uy * vx + vy * vy;
            ps[j] = clip1(1.0e-4f * (ddp + rhs));
        }

        float* dr = div_out + ((size_t)b * OH + h) * WW + wc;
        *(float4*)dr = make_float4(dv[0], dv[1], dv[2], dv[3]);

        // pstar rows are 510 floats -> only 8B aligned; use float2 stores
        float* pr = ps_out + ((size_t)b * OH + h) * OW2 + wc;
        *(float2*)pr = make_float2(ps[0], ps[1]);
        if (wc + 2 < OW2) *(float2*)(pr + 2) = make_float2(ps[2], ps[3]);
    }
}

extern "C" void kernel_launch(void* const* d_in, const int* in_sizes, int n_in,
                              void* d_out, int out_size, void* d_ws, size_t ws_size,
                              hipStream_t stream) {
    const float* uPred = (const float*)d_in[0];
    const float* pPred = (const float*)d_in[1];
    float* div_out = (float*)d_out;
    float* ps_out  = div_out + (size_t)BN * OH * WW;

    pcles_kernel<<<dim3(NBLK), dim3(128), 0, stream>>>(uPred, pPred, div_out, ps_out);
}

// Round 3
// 29.754 us; speedup vs baseline: 1.8444x; 1.3031x over previous
//
#include <hip/hip_runtime.h>

// PhysConstrainedLES: fused divergence + pressure-Poisson RHS stencils.
// uPred: [B,2,H,W] f32, pPred: [B,1,H,W] f32
// out:  div [B,510,512] then pstar [B,510,510], concatenated flat, f32.
//
// One output row per thread-row: 16320 blocks x 128 threads, 4 cols/thread.
// Halo columns via wave shuffles (lanes 0/63 fall back to clamped scalar
// loads, which also realizes the replicate-pad edge semantics). Vertical
// 3-row reuse is delegated to L2 via the bijective XCD swizzle (consecutive
// blocks on one XCD process consecutive rows of the same batch).

#define BN 32
#define HH 512
#define WW 512
#define OH 510
#define OW2 510
#define NBLK (OH * BN)   // 16320, divisible by 8

__device__ __forceinline__ float clip1(float x) {
    return fminf(fmaxf(x, -1.0f), 1.0f);
}

__global__ __launch_bounds__(128) void pcles_kernel(
    const float* __restrict__ u_,   // [B,2,H,W]
    const float* __restrict__ p_,   // [B,1,H,W]
    float* __restrict__ div_out,    // [B,510,512]
    float* __restrict__ ps_out)     // [B,510,510]
{
    // bijective XCD swizzle: XCD k gets nb in [k*2040, (k+1)*2040) ->
    // consecutive h within a batch on one XCD -> vertical reuse in its L2.
    const int bid = blockIdx.x;
    const int nb  = (bid & 7) * (NBLK / 8) + (bid >> 3);
    const int b   = nb / OH;
    const int h   = nb % OH;

    const int tid  = (int)threadIdx.x;
    const int wc   = tid * 4;        // 0..508
    const int lane = tid & 63;

    const float* ub = u_ + (size_t)b * 2 * HH * WW;
    const float* vb = ub + HH * WW;
    const float* pb = p_ + (size_t)b * HH * WW;

    const float* ur0 = ub + h * WW;          // rows h, h+1, h+2
    const float* vr0 = vb + h * WW;
    const float* pr0 = pb + h * WW;

    // 9 independent vector loads (MLP)
    const float4 tu0 = *(const float4*)(ur0 + wc);
    const float4 tu1 = *(const float4*)(ur0 + WW + wc);
    const float4 tu2 = *(const float4*)(ur0 + 2 * WW + wc);
    const float4 tv0 = *(const float4*)(vr0 + wc);
    const float4 tv1 = *(const float4*)(vr0 + WW + wc);
    const float4 tv2 = *(const float4*)(vr0 + 2 * WW + wc);
    const float4 tp0 = *(const float4*)(pr0 + wc);
    const float4 tp1 = *(const float4*)(pr0 + WW + wc);
    const float4 tp2 = *(const float4*)(pr0 + 2 * WW + wc);

    // halo columns via shuffles (wave-internal); fix wave-edge lanes below
    float uL1   = __shfl_up(tu1.w, 1);     // col wc-1, row h+1
    float uR1_0 = __shfl_down(tu0.x, 1);   // col wc+4, row h
    float uR1_1 = __shfl_down(tu1.x, 1);   // col wc+4, row h+1
    float uR1_2 = __shfl_down(tu2.x, 1);   // col wc+4, row h+2
    float uR2_1 = __shfl_down(tu1.y, 1);   // col wc+5, row h+1
    float vR1_0 = __shfl_down(tv0.x, 1);
    float vR1_1 = __shfl_down(tv1.x, 1);
    float vR1_2 = __shfl_down(tv2.x, 1);
    float vR2_1 = __shfl_down(tv1.y, 1);
    float pR1_0 = __shfl_down(tp0.x, 1);
    float pR1_1 = __shfl_down(tp1.x, 1);
    float pR1_2 = __shfl_down(tp2.x, 1);
    float pR2_1 = __shfl_down(tp1.y, 1);

    const int cL = (wc > 0) ? wc - 1 : 0;              // replicate-pad clamp
    const int c4 = (wc + 4 < WW) ? wc + 4 : WW - 1;
    const int c5 = (wc + 5 < WW) ? wc + 5 : WW - 1;
    if (lane == 0)  uL1 = ur0[WW + cL];
    if (lane == 63) {
        uR1_0 = ur0[c4];          uR1_1 = ur0[WW + c4];  uR1_2 = ur0[2 * WW + c4];
        uR2_1 = ur0[WW + c5];
        vR1_0 = vr0[c4];          vR1_1 = vr0[WW + c4];  vR1_2 = vr0[2 * WW + c4];
        vR2_1 = vr0[WW + c5];
        pR1_0 = pr0[c4];          pR1_1 = pr0[WW + c4];  pR1_2 = pr0[2 * WW + c4];
        pR2_1 = pr0[WW + c5];
    }

    // register windows (constant-indexed -> stay in VGPRs)
    const float u0[5] = {tu0.x, tu0.y, tu0.z, tu0.w, uR1_0};             // cols wc..wc+4
    const float u1[7] = {uL1, tu1.x, tu1.y, tu1.z, tu1.w, uR1_1, uR2_1}; // cols wc-1..wc+5
    const float u2[5] = {tu2.x, tu2.y, tu2.z, tu2.w, uR1_2};
    const float v0[5] = {tv0.x, tv0.y, tv0.z, tv0.w, vR1_0};
    const float v1[6] = {tv1.x, tv1.y, tv1.z, tv1.w, vR1_1, vR2_1};     // cols wc..wc+5
    const float v2[5] = {tv2.x, tv2.y, tv2.z, tv2.w, vR1_2};
    const float p0[5] = {tp0.x, tp0.y, tp0.z, tp0.w, pR1_0};
    const float p1[6] = {tp1.x, tp1.y, tp1.z, tp1.w, pR1_1, pR2_1};
    const float p2[5] = {tp2.x, tp2.y, tp2.z, tp2.w, pR1_2};

    float dv[4], ps[4];
    #pragma unroll
    for (int j = 0; j < 4; ++j) {
        const float dudx = (u1[j + 2] - u1[j]) * 50.0f;
        const float dvdy = (v2[j] - v0[j]) * 50.0f;
        dv[j] = clip1(0.01f * (dvdy + dudx));

        const float pc  = p1[j + 1];
        const float ddp = (p1[j] - 2.0f * pc + p1[j + 2]) * 1.0e4f
                        + (p0[j + 1] - 2.0f * pc + p2[j + 1]) * 1.0e4f;
        const float ux = (u1[j + 3] - u1[j + 1]) * 50.0f;
        const float uy = (u2[j + 1] - u0[j + 1]) * 50.0f;
        const float vx = (v1[j + 2] - v1[j]) * 50.0f;
        const float vy = (v2[j + 1] - v0[j + 1]) * 50.0f;
        const float rhs = ux * ux + 2.0f * uy * vx + vy * vy;
        ps[j] = clip1(1.0e-4f * (ddp + rhs));
    }

    float* dr = div_out + ((size_t)b * OH + h) * WW + wc;
    *(float4*)dr = make_float4(dv[0], dv[1], dv[2], dv[3]);

    // pstar rows are 510 floats -> only 8B aligned; float2 stores
    float* pr = ps_out + ((size_t)b * OH + h) * OW2 + wc;
    *(float2*)pr = make_float2(ps[0], ps[1]);
    if (wc + 2 < OW2) *(float2*)(pr + 2) = make_float2(ps[2], ps[3]);
}

extern "C" void kernel_launch(void* const* d_in, const int* in_sizes, int n_in,
                              void* d_out, int out_size, void* d_ws, size_t ws_size,
                              hipStream_t stream) {
    const float* uPred = (const float*)d_in[0];
    const float* pPred = (const float*)d_in[1];
    float* div_out = (float*)d_out;
    float* ps_out  = div_out + (size_t)BN * OH * WW;

    pcles_kernel<<<dim3(NBLK), dim3(128), 0, stream>>>(uPred, pPred, div_out, ps_out);
}